// Round 4
// baseline (2812.842 us; speedup 1.0000x reference)
//
#include <hip/hip_runtime.h>
#include <math.h>

#define NV  10
#define H1  64
#define H2  32

// ---------------------------------------------------------------------------
// Kernel 1: adjacency + weight folding.
//  - W = sigmoid(W_logits), zero diag, top-30 mask -> Wout (output #1 tail)
//  - W1eff[j,h,i] = W1[j,h,i] * W[i,j]  -> d_ws   (folds the per-sample
//    xj = x*W[:,j] multiply into the layer-1 weights, done once)
// ---------------------------------------------------------------------------
__global__ void prep_W(const float* __restrict__ Wl,
                       const float* __restrict__ W1,
                       float* __restrict__ Wout,
                       float* __restrict__ W1eff) {
    __shared__ float W[100];
    __shared__ float thrv;
    int t = threadIdx.x;   // 128 threads
    if (t < 100) {
        int i = t / NV, j = t % NV;
        float w = 1.0f / (1.0f + expf(-Wl[t]));
        if (i == j) w = 0.0f;
        W[t] = w;
    }
    __syncthreads();
    float v = (t < 100) ? W[t] : 0.0f;
    if (t < 100) {
        int cnt = 0;
        #pragma unroll
        for (int k = 0; k < 100; ++k) cnt += (W[k] > v) ? 1 : 0;
        if (cnt == 29) thrv = v;   // exactly 29 strictly greater == 30th largest
    }
    __syncthreads();
    if (t < 100) {
        float m = (v >= thrv) ? v : 0.0f;
        Wout[t] = m;
        W[t] = m;                   // reuse shared for folding below
    }
    __syncthreads();
    // fold adjacency into layer-1 weights: 6400 entries over 128 threads
    for (int idx = t; idx < NV * H1 * NV; idx += 128) {
        int i = idx % NV;
        int j = idx / (H1 * NV);
        W1eff[idx] = W1[idx] * W[i * NV + j];
    }
}

// ---------------------------------------------------------------------------
// Main kernel: one sample per thread, fused layers, static-indexed s2[32]
// (rule #20). Weights wave-uniform -> s_load. GELU = tanh-form approximation:
// max |err| vs exact ~5e-4, propagates to <3e-3 at output (threshold 1.79e-2).
// ---------------------------------------------------------------------------
__device__ __forceinline__ float gelu_fast(float x) {
    // 0.5x(1+tanh(c(x+0.044715x^3))) ; tanh(y)=1-2/(1+e^{2y})
    // => gelu = x - x / (1 + exp2(K * x * (1 + 0.044715 x^2)))
    const float K = 2.0f * 0.7978845608028654f * 1.4426950408889634f; // 2c*log2e
    float x2 = x * x;
    float t  = __builtin_fmaf(0.044715f, x2, 1.0f);
    float y  = K * x * t;
    float e  = exp2f(y);               // v_exp_f32
    float d  = e + 1.0f;
    float r  = __frcp_rn(d);           // v_rcp-based
    return __builtin_fmaf(-x, r, x);   // x - x/d
}

__global__ __launch_bounds__(256, 4) void ncd_main(
    const float* __restrict__ X,      // [B,10]
    const float* __restrict__ W1e,    // [10,64,10]  adjacency-folded
    const float* __restrict__ b1,     // [10,64]
    const float* __restrict__ W2,     // [10,32,64]
    const float* __restrict__ b2,     // [10,32]
    const float* __restrict__ W3,     // [10,32]
    const float* __restrict__ b3,     // [10]
    float* __restrict__ out,          // [B,10]
    int B)
{
    int b = blockIdx.x * blockDim.x + threadIdx.x;
    if (b >= B) return;

    float x[NV];
    #pragma unroll
    for (int i = 0; i < 5; ++i) {
        float2 v = *reinterpret_cast<const float2*>(X + (size_t)b * NV + 2 * i);
        x[2 * i] = v.x; x[2 * i + 1] = v.y;
    }

    float res[NV];
    #pragma unroll 1
    for (int j = 0; j < NV; ++j) {
        float s2[H2];
        #pragma unroll
        for (int o = 0; o < H2; ++o) s2[o] = b2[j * H2 + o];

        const float* w1  = W1e + j * (H1 * NV);
        const float* w2  = W2  + j * (H2 * H1);
        const float* bb1 = b1  + j * H1;

        // stream hidden units: g = gelu(b1 + x.w1row); s2[o] += g * W2[o][h]
        #pragma unroll 8
        for (int h = 0; h < H1; ++h) {
            float s = bb1[h];
            const float* w = w1 + h * NV;
            #pragma unroll
            for (int i = 0; i < NV; ++i) s += x[i] * w[i];
            float g = gelu_fast(s);
            #pragma unroll
            for (int o = 0; o < H2; ++o) s2[o] += g * w2[o * H1 + h];
        }

        float r = b3[j];
        #pragma unroll
        for (int o = 0; o < H2; ++o) r += gelu_fast(s2[o]) * W3[j * H2 + o];
        res[j] = r;
    }

    #pragma unroll
    for (int i = 0; i < 5; ++i) {
        float2 v; v.x = res[2 * i]; v.y = res[2 * i + 1];
        *reinterpret_cast<float2*>(out + (size_t)b * NV + 2 * i) = v;
    }
}

extern "C" void kernel_launch(void* const* d_in, const int* in_sizes, int n_in,
                              void* d_out, int out_size, void* d_ws, size_t ws_size,
                              hipStream_t stream) {
    const float* X  = (const float*)d_in[0];
    const float* Wl = (const float*)d_in[1];
    const float* W1 = (const float*)d_in[2];
    const float* b1 = (const float*)d_in[3];
    const float* W2 = (const float*)d_in[4];
    const float* b2 = (const float*)d_in[5];
    const float* W3 = (const float*)d_in[6];
    const float* b3 = (const float*)d_in[7];
    float* out = (float*)d_out;

    int B = in_sizes[0] / NV;                 // 500000
    float* Wout  = out + (size_t)B * NV;      // output #2 (10x10 W) at the tail
    float* W1eff = (float*)d_ws;              // 6400 floats of scratch

    hipLaunchKernelGGL(prep_W, dim3(1), dim3(128), 0, stream, Wl, W1, Wout, W1eff);

    int grid = (B + 255) / 256;
    hipLaunchKernelGGL(ncd_main, dim3(grid), dim3(256), 0, stream,
                       X, W1eff, b1, W2, b2, W3, b3, out, B);
}

// Round 5
// 2810.740 us; speedup vs baseline: 1.0007x; 1.0007x over previous
//
#include <hip/hip_runtime.h>
#include <math.h>

#define NV  10
#define H1  64
#define H2  32

// ---------------------------------------------------------------------------
// Kernel 1: adjacency + weight folding.
//  - W = sigmoid(W_logits), zero diag, top-30 mask -> Wout (output #1 tail)
//  - W1eff[j,h,i] = W1[j,h,i] * W[i,j]  -> d_ws   (folds the per-sample
//    xj = x*W[:,j] multiply into the layer-1 weights, done once)
// ---------------------------------------------------------------------------
__global__ void prep_W(const float* __restrict__ Wl,
                       const float* __restrict__ W1,
                       float* __restrict__ Wout,
                       float* __restrict__ W1eff) {
    __shared__ float W[100];
    __shared__ float thrv;
    int t = threadIdx.x;   // 128 threads
    if (t < 100) {
        int i = t / NV, j = t % NV;
        float w = 1.0f / (1.0f + expf(-Wl[t]));
        if (i == j) w = 0.0f;
        W[t] = w;
    }
    __syncthreads();
    float v = (t < 100) ? W[t] : 0.0f;
    if (t < 100) {
        int cnt = 0;
        #pragma unroll
        for (int k = 0; k < 100; ++k) cnt += (W[k] > v) ? 1 : 0;
        if (cnt == 29) thrv = v;   // exactly 29 strictly greater == 30th largest
    }
    __syncthreads();
    if (t < 100) {
        float m = (v >= thrv) ? v : 0.0f;
        Wout[t] = m;
        W[t] = m;                   // reuse shared for folding below
    }
    __syncthreads();
    // fold adjacency into layer-1 weights: 6400 entries over 128 threads
    for (int idx = t; idx < NV * H1 * NV; idx += 128) {
        int i = idx % NV;
        int j = idx / (H1 * NV);
        W1eff[idx] = W1[idx] * W[i * NV + j];
    }
}

// ---------------------------------------------------------------------------
// Main kernel: one sample per thread, fused layers, static-indexed s2[32]
// (rule #20). Weights wave-uniform -> s_load. GELU: tanh-form, 7 VALU ops,
// hardware v_rcp_f32 (round 3's __frcp_rn expanded to the exact-div sequence
// and cost 3.6x total runtime -- no correctly-rounded rcp exists on gfx950).
// ---------------------------------------------------------------------------
__device__ __forceinline__ float gelu_fast(float x) {
    // gelu = x - x / (1 + exp2(K*x*(1 + 0.044715 x^2)))
    const float K  = 2.0f * 0.7978845608028654f * 1.4426950408889634f; // 2c*log2e
    const float K2 = K * 0.044715f;
    float x2 = x * x;
    float t  = __builtin_fmaf(K2, x2, K);     // K*(1+0.044715 x^2)
    float y  = x * t;
    float e  = exp2f(y);                      // v_exp_f32 (TRANS)
    float d  = e + 1.0f;
    float r  = __builtin_amdgcn_rcpf(d);      // v_rcp_f32 (TRANS, ~1ulp)
    return __builtin_fmaf(-x, r, x);          // x - x/d
}

__global__ __launch_bounds__(256, 4) void ncd_main(
    const float* __restrict__ X,      // [B,10]
    const float* __restrict__ W1e,    // [10,64,10]  adjacency-folded
    const float* __restrict__ b1,     // [10,64]
    const float* __restrict__ W2,     // [10,32,64]
    const float* __restrict__ b2,     // [10,32]
    const float* __restrict__ W3,     // [10,32]
    const float* __restrict__ b3,     // [10]
    float* __restrict__ out,          // [B,10]
    int B)
{
    int b = blockIdx.x * blockDim.x + threadIdx.x;
    if (b >= B) return;

    float x[NV];
    #pragma unroll
    for (int i = 0; i < 5; ++i) {
        float2 v = *reinterpret_cast<const float2*>(X + (size_t)b * NV + 2 * i);
        x[2 * i] = v.x; x[2 * i + 1] = v.y;
    }

    float res[NV];
    #pragma unroll 1
    for (int j = 0; j < NV; ++j) {
        float s2[H2];
        #pragma unroll
        for (int o = 0; o < H2; ++o) s2[o] = b2[j * H2 + o];

        const float* w1  = W1e + j * (H1 * NV);
        const float* w2  = W2  + j * (H2 * H1);
        const float* bb1 = b1  + j * H1;

        // stream hidden units: g = gelu(b1 + x.w1row); s2[o] += g * W2[o][h]
        #pragma unroll 8
        for (int h = 0; h < H1; ++h) {
            float s = bb1[h];
            const float* w = w1 + h * NV;
            #pragma unroll
            for (int i = 0; i < NV; ++i) s += x[i] * w[i];
            float g = gelu_fast(s);
            #pragma unroll
            for (int o = 0; o < H2; ++o) s2[o] += g * w2[o * H1 + h];
        }

        float r = b3[j];
        #pragma unroll
        for (int o = 0; o < H2; ++o) r += gelu_fast(s2[o]) * W3[j * H2 + o];
        res[j] = r;
    }

    #pragma unroll
    for (int i = 0; i < 5; ++i) {
        float2 v; v.x = res[2 * i]; v.y = res[2 * i + 1];
        *reinterpret_cast<float2*>(out + (size_t)b * NV + 2 * i) = v;
    }
}

extern "C" void kernel_launch(void* const* d_in, const int* in_sizes, int n_in,
                              void* d_out, int out_size, void* d_ws, size_t ws_size,
                              hipStream_t stream) {
    const float* X  = (const float*)d_in[0];
    const float* Wl = (const float*)d_in[1];
    const float* W1 = (const float*)d_in[2];
    const float* b1 = (const float*)d_in[3];
    const float* W2 = (const float*)d_in[4];
    const float* b2 = (const float*)d_in[5];
    const float* W3 = (const float*)d_in[6];
    const float* b3 = (const float*)d_in[7];
    float* out = (float*)d_out;

    int B = in_sizes[0] / NV;                 // 500000
    float* Wout  = out + (size_t)B * NV;      // output #2 (10x10 W) at the tail
    float* W1eff = (float*)d_ws;              // 6400 floats of scratch

    hipLaunchKernelGGL(prep_W, dim3(1), dim3(128), 0, stream, Wl, W1, Wout, W1eff);

    int grid = (B + 255) / 256;
    hipLaunchKernelGGL(ncd_main, dim3(grid), dim3(256), 0, stream,
                       X, W1eff, b1, W2, b2, W3, b3, out, B);
}

// Round 6
// 1395.789 us; speedup vs baseline: 2.0152x; 2.0137x over previous
//
#include <hip/hip_runtime.h>
#include <math.h>

#define NV  10
#define H1  64
#define H2  32

// ---------------------------------------------------------------------------
// Kernel 1: adjacency. W = sigmoid(W_logits) with zeroed diagonal; keep only
// entries >= 30th-largest value (top-k mask), write masked W (output #1 tail).
// (Exact round-2 version: no weight folding -- single-variable A/B vs round 2.)
// ---------------------------------------------------------------------------
__global__ void prep_W(const float* __restrict__ Wl, float* __restrict__ Wout) {
    __shared__ float W[100];
    __shared__ float thrv;
    int t = threadIdx.x;
    if (t < 100) {
        int i = t / NV, j = t % NV;
        float w = 1.0f / (1.0f + expf(-Wl[t]));
        if (i == j) w = 0.0f;
        W[t] = w;
    }
    __syncthreads();
    if (t < 100) {
        float v = W[t];
        int cnt = 0;
        #pragma unroll
        for (int k = 0; k < 100; ++k) cnt += (W[k] > v) ? 1 : 0;
        if (cnt == 29) thrv = v;   // exactly 29 strictly greater == 30th largest
    }
    __syncthreads();
    if (t < 100) {
        float v = W[t];
        Wout[t] = (v >= thrv) ? v : 0.0f;
    }
}

// ---------------------------------------------------------------------------
// Main kernel: EXACT round-2 structure (777us, VGPR 64, no spill), with the
// single change: erff-GELU -> tanh-form GELU using RAW hardware builtins
// (v_exp_f32 + v_rcp_f32; no OCML). Max |err| vs exact gelu ~5e-4.
// ---------------------------------------------------------------------------
__device__ __forceinline__ float gelu_fast(float x) {
    // gelu = x - x / (1 + exp2(K*x*(1 + 0.044715 x^2)))
    const float K  = 2.3022585092994046f;     // 2*0.7978845608*log2(e)
    const float K2 = 0.10294549049280418f;    // K*0.044715
    float x2 = x * x;
    float t  = __builtin_fmaf(K2, x2, K);
    float y  = x * t;
    float e  = __builtin_amdgcn_exp2f(y);     // v_exp_f32 (TRANS)
    float r  = __builtin_amdgcn_rcpf(e + 1.0f); // v_rcp_f32 (TRANS)
    return __builtin_fmaf(-x, r, x);          // x - x/(1+e)
}

__global__ __launch_bounds__(256, 4) void ncd_main(
    const float* __restrict__ X,    // [B,10]
    const float* __restrict__ Wm,   // [10,10] masked adjacency
    const float* __restrict__ W1,   // [10,64,10]
    const float* __restrict__ b1,   // [10,64]
    const float* __restrict__ W2,   // [10,32,64]
    const float* __restrict__ b2,   // [10,32]
    const float* __restrict__ W3,   // [10,32]
    const float* __restrict__ b3,   // [10]
    float* __restrict__ out,        // [B,10]
    int B)
{
    int b = blockIdx.x * blockDim.x + threadIdx.x;
    if (b >= B) return;

    float x[NV];
    #pragma unroll
    for (int i = 0; i < 5; ++i) {
        float2 v = *reinterpret_cast<const float2*>(X + (size_t)b * NV + 2 * i);
        x[2 * i] = v.x; x[2 * i + 1] = v.y;
    }

    float res[NV];
    #pragma unroll 1
    for (int j = 0; j < NV; ++j) {
        // fold adjacency column j into the input once
        float xj[NV];
        #pragma unroll
        for (int i = 0; i < NV; ++i) xj[i] = x[i] * Wm[i * NV + j];

        // layer-2 accumulators (static indices only -> registers)
        float s2[H2];
        #pragma unroll
        for (int o = 0; o < H2; ++o) s2[o] = b2[j * H2 + o];

        const float* w1  = W1 + j * (H1 * NV);
        const float* w2  = W2 + j * (H2 * H1);
        const float* bb1 = b1 + j * H1;

        // stream over hidden units: g = gelu(b1 + xj.w1row); s2[o] += g*W2[o][h]
        #pragma unroll 4
        for (int h = 0; h < H1; ++h) {
            float s = bb1[h];
            const float* w = w1 + h * NV;
            #pragma unroll
            for (int i = 0; i < NV; ++i) s += xj[i] * w[i];
            float g = gelu_fast(s);
            #pragma unroll
            for (int o = 0; o < H2; ++o) s2[o] += g * w2[o * H1 + h];
        }

        // head
        float r = b3[j];
        #pragma unroll
        for (int o = 0; o < H2; ++o) r += gelu_fast(s2[o]) * W3[j * H2 + o];
        res[j] = r;
    }

    #pragma unroll
    for (int i = 0; i < 5; ++i) {
        float2 v; v.x = res[2 * i]; v.y = res[2 * i + 1];
        *reinterpret_cast<float2*>(out + (size_t)b * NV + 2 * i) = v;
    }
}

extern "C" void kernel_launch(void* const* d_in, const int* in_sizes, int n_in,
                              void* d_out, int out_size, void* d_ws, size_t ws_size,
                              hipStream_t stream) {
    const float* X  = (const float*)d_in[0];
    const float* Wl = (const float*)d_in[1];
    const float* W1 = (const float*)d_in[2];
    const float* b1 = (const float*)d_in[3];
    const float* W2 = (const float*)d_in[4];
    const float* b2 = (const float*)d_in[5];
    const float* W3 = (const float*)d_in[6];
    const float* b3 = (const float*)d_in[7];
    float* out = (float*)d_out;

    int B = in_sizes[0] / NV;                 // 500000
    float* Wout = out + (size_t)B * NV;       // output #2 (10x10 W) lives at the tail

    hipLaunchKernelGGL(prep_W, dim3(1), dim3(128), 0, stream, Wl, Wout);

    int grid = (B + 255) / 256;
    hipLaunchKernelGGL(ncd_main, dim3(grid), dim3(256), 0, stream,
                       X, Wout, W1, b1, W2, b2, W3, b3, out, B);
}

// Round 7
// 1328.560 us; speedup vs baseline: 2.1172x; 1.0506x over previous
//
#include <hip/hip_runtime.h>
#include <math.h>

#define NV  10
#define H1  64
#define H2  32
#define TBL_N 513   // gelu table over x in [-8, 8], step 1/32

// ---------------------------------------------------------------------------
// Kernel 1: adjacency (sigmoid + zero-diag + top-30 mask -> output #1 tail)
// plus: exact-GELU lookup table (513 entries, erff evaluated ONCE here,
// never in the hot loop -- transcendentals measured ~30-50 cyc/wave-instr
// on this chip, rounds 3-5).
// ---------------------------------------------------------------------------
__global__ void prep_W(const float* __restrict__ Wl,
                       float* __restrict__ Wout,
                       float* __restrict__ gtbl) {
    __shared__ float W[100];
    __shared__ float thrv;
    int t = threadIdx.x;   // 128 threads
    if (t < 100) {
        int i = t / NV, j = t % NV;
        float w = 1.0f / (1.0f + expf(-Wl[t]));
        if (i == j) w = 0.0f;
        W[t] = w;
    }
    __syncthreads();
    if (t < 100) {
        float v = W[t];
        int cnt = 0;
        #pragma unroll
        for (int k = 0; k < 100; ++k) cnt += (W[k] > v) ? 1 : 0;
        if (cnt == 29) thrv = v;   // exactly 29 strictly greater == 30th largest
    }
    __syncthreads();
    if (t < 100) {
        float v = W[t];
        Wout[t] = (v >= thrv) ? v : 0.0f;
    }
    // gelu table: gtbl[i] = gelu_exact(-8 + i/32)
    for (int i = t; i < TBL_N; i += 128) {
        float x = -8.0f + (float)i * 0.03125f;
        gtbl[i] = 0.5f * x * (1.0f + erff(x * 0.70710678118654752440f));
    }
}

// ---------------------------------------------------------------------------
// Main kernel: round-2 structure (fused layers, static s2[32], wave-uniform
// weight reads -> s_load). GELU via piecewise-linear LDS table:
// ~9 full-rate VALU ops + 1 ds_read2_b32, zero transcendentals.
// Interp error <= ~1e-4 (|gelu''|max ~0.8, step 1/32); x>8 -> x exactly.
// ---------------------------------------------------------------------------
__device__ __forceinline__ float gelu_lut(float x, const float* __restrict__ tbl) {
    float t  = __builtin_fmaf(x, 32.0f, 256.0f);          // index space
    t        = __builtin_amdgcn_fmed3f(t, 0.0f, 511.999f); // clamp (1 op)
    float ff = floorf(t);
    float f  = t - ff;
    int   i  = (int)ff;
    float v0 = tbl[i];
    float v1 = tbl[i + 1];                                 // ds_read2_b32 pair
    float y  = __builtin_fmaf(f, v1 - v0, v0);
    return (x > 8.0f) ? x : y;                             // exact tail
}

__global__ __launch_bounds__(256, 4) void ncd_main(
    const float* __restrict__ X,    // [B,10]
    const float* __restrict__ Wm,   // [10,10] masked adjacency
    const float* __restrict__ W1,   // [10,64,10]
    const float* __restrict__ b1,   // [10,64]
    const float* __restrict__ W2,   // [10,32,64]
    const float* __restrict__ b2,   // [10,32]
    const float* __restrict__ W3,   // [10,32]
    const float* __restrict__ b3,   // [10]
    const float* __restrict__ gtbl, // [513] gelu table
    float* __restrict__ out,        // [B,10]
    int B)
{
    __shared__ float tbl[TBL_N];
    for (int i = threadIdx.x; i < TBL_N; i += 256) tbl[i] = gtbl[i];
    __syncthreads();

    int b = blockIdx.x * blockDim.x + threadIdx.x;
    if (b >= B) return;

    float x[NV];
    #pragma unroll
    for (int i = 0; i < 5; ++i) {
        float2 v = *reinterpret_cast<const float2*>(X + (size_t)b * NV + 2 * i);
        x[2 * i] = v.x; x[2 * i + 1] = v.y;
    }

    float res[NV];
    #pragma unroll 1
    for (int j = 0; j < NV; ++j) {
        // fold adjacency column j into the input once
        float xj[NV];
        #pragma unroll
        for (int i = 0; i < NV; ++i) xj[i] = x[i] * Wm[i * NV + j];

        // layer-2 accumulators (static indices only -> registers)
        float s2[H2];
        #pragma unroll
        for (int o = 0; o < H2; ++o) s2[o] = b2[j * H2 + o];

        const float* w1  = W1 + j * (H1 * NV);
        const float* w2  = W2 + j * (H2 * H1);
        const float* bb1 = b1 + j * H1;

        // stream over hidden units: g = gelu(b1 + xj.w1row); s2[o] += g*W2[o][h]
        #pragma unroll 4
        for (int h = 0; h < H1; ++h) {
            float s = bb1[h];
            const float* w = w1 + h * NV;
            #pragma unroll
            for (int i = 0; i < NV; ++i) s += xj[i] * w[i];
            float g = gelu_lut(s, tbl);
            #pragma unroll
            for (int o = 0; o < H2; ++o) s2[o] += g * w2[o * H1 + h];
        }

        // head
        float r = b3[j];
        #pragma unroll
        for (int o = 0; o < H2; ++o) r += gelu_lut(s2[o], tbl) * W3[j * H2 + o];
        res[j] = r;
    }

    #pragma unroll
    for (int i = 0; i < 5; ++i) {
        float2 v; v.x = res[2 * i]; v.y = res[2 * i + 1];
        *reinterpret_cast<float2*>(out + (size_t)b * NV + 2 * i) = v;
    }
}

extern "C" void kernel_launch(void* const* d_in, const int* in_sizes, int n_in,
                              void* d_out, int out_size, void* d_ws, size_t ws_size,
                              hipStream_t stream) {
    const float* X  = (const float*)d_in[0];
    const float* Wl = (const float*)d_in[1];
    const float* W1 = (const float*)d_in[2];
    const float* b1 = (const float*)d_in[3];
    const float* W2 = (const float*)d_in[4];
    const float* b2 = (const float*)d_in[5];
    const float* W3 = (const float*)d_in[6];
    const float* b3 = (const float*)d_in[7];
    float* out = (float*)d_out;

    int B = in_sizes[0] / NV;                 // 500000
    float* Wout = out + (size_t)B * NV;       // output #2 (10x10 W) at the tail
    float* gtbl = (float*)d_ws;               // 513 floats of scratch

    hipLaunchKernelGGL(prep_W, dim3(1), dim3(128), 0, stream, Wl, Wout, gtbl);

    int grid = (B + 255) / 256;
    hipLaunchKernelGGL(ncd_main, dim3(grid), dim3(256), 0, stream,
                       X, Wout, W1, b1, W2, b2, W3, b3, gtbl, out, B);
}

// Round 8
// 542.435 us; speedup vs baseline: 5.1856x; 2.4493x over previous
//
#include <hip/hip_runtime.h>
#include <math.h>

#define NV  10
#define H1  64
#define H2  32
#define TBL_N 513   // gelu table over x in [-8, 8], step 1/32

// d_ws layout (floats): [0,513) gelu table | [513, 513+6400) W1eff | then W2T 20480
#define WS_TBL  0
#define WS_W1E  513
#define WS_W2T  (513 + NV * H1 * NV)

// ---------------------------------------------------------------------------
// Prep (1 block): adjacency mask -> Wout(output tail); gelu LUT (exact erff,
// evaluated once); W1eff[j,h,i] = W1[j,h,i]*W[i,j] (adjacency folded);
// W2T[j,h,o] = W2[j,o,h] (transposed so the hot loop reads contiguous rows).
// ---------------------------------------------------------------------------
__global__ void prep_W(const float* __restrict__ Wl,
                       const float* __restrict__ W1,
                       const float* __restrict__ W2,
                       float* __restrict__ Wout,
                       float* __restrict__ ws) {
    __shared__ float W[100];
    __shared__ float thrv;
    int t = threadIdx.x;   // 256 threads
    if (t < 100) {
        int i = t / NV, j = t % NV;
        float w = 1.0f / (1.0f + expf(-Wl[t]));
        if (i == j) w = 0.0f;
        W[t] = w;
    }
    __syncthreads();
    if (t < 100) {
        float v = W[t];
        int cnt = 0;
        #pragma unroll
        for (int k = 0; k < 100; ++k) cnt += (W[k] > v) ? 1 : 0;
        if (cnt == 29) thrv = v;   // exactly 29 strictly greater == 30th largest
    }
    __syncthreads();
    if (t < 100) {
        float v = W[t];
        float m = (v >= thrv) ? v : 0.0f;
        Wout[t] = m;
        W[t] = m;
    }
    __syncthreads();
    // gelu table
    for (int i = t; i < TBL_N; i += 256) {
        float x = -8.0f + (float)i * 0.03125f;
        ws[WS_TBL + i] = 0.5f * x * (1.0f + erff(x * 0.70710678118654752440f));
    }
    // W1eff: fold adjacency column into layer-1 weights
    for (int idx = t; idx < NV * H1 * NV; idx += 256) {
        int i = idx % NV;
        int j = idx / (H1 * NV);
        ws[WS_W1E + idx] = W1[idx] * W[i * NV + j];
    }
    // W2T[j][h][o] = W2[j][o][h]
    for (int idx = t; idx < NV * H1 * H2; idx += 256) {
        int o = idx % H2;
        int h = (idx / H2) % H1;
        int j = idx / (H1 * H2);
        ws[WS_W2T + idx] = W2[j * (H2 * H1) + o * H1 + h];
    }
}

// ---------------------------------------------------------------------------
// Main: one sample/thread, fused layers, static s2[32]. h-loop deliberately
// NOT unrolled: with branch-free GELU + unroll>=4 the scheduler pipelines
// h-iterations, live ranges explode, and the allocator shuttles s2[] through
// AGPRs (v_accvgpr_read/write tripled VALU issue in rounds 3-6; VGPR 64->40
// with zero scratch traffic was the tell). One h in flight keeps the live
// set ~60 VGPR. W2T rows are contiguous -> s_load_dwordx8 batches.
// ---------------------------------------------------------------------------
__device__ __forceinline__ float gelu_lut(float x, const float* __restrict__ tbl) {
    float t  = __builtin_fmaf(x, 32.0f, 256.0f);           // index space
    t        = __builtin_amdgcn_fmed3f(t, 0.0f, 511.999f); // clamp
    float ff = floorf(t);
    float f  = t - ff;
    int   i  = (int)ff;
    float v0 = tbl[i];
    float v1 = tbl[i + 1];                                 // ds_read2_b32 pair
    float y  = __builtin_fmaf(f, v1 - v0, v0);
    return (x > 8.0f) ? x : y;                             // exact tail
}

__global__ __launch_bounds__(256, 4) void ncd_main(
    const float* __restrict__ X,      // [B,10]
    const float* __restrict__ W1e,    // [10,64,10] adjacency-folded (ws)
    const float* __restrict__ b1,     // [10,64]
    const float* __restrict__ W2T,    // [10,64,32] transposed (ws)
    const float* __restrict__ b2,     // [10,32]
    const float* __restrict__ W3,     // [10,32]
    const float* __restrict__ b3,     // [10]
    const float* __restrict__ gtbl,   // [513] gelu table (ws)
    float* __restrict__ out,          // [B,10]
    int B)
{
    __shared__ float tbl[TBL_N];
    for (int i = threadIdx.x; i < TBL_N; i += 256) tbl[i] = gtbl[i];
    __syncthreads();

    int b = blockIdx.x * blockDim.x + threadIdx.x;
    if (b >= B) return;

    float x[NV];
    #pragma unroll
    for (int i = 0; i < 5; ++i) {
        float2 v = *reinterpret_cast<const float2*>(X + (size_t)b * NV + 2 * i);
        x[2 * i] = v.x; x[2 * i + 1] = v.y;
    }

    float res[NV];
    #pragma unroll 1
    for (int j = 0; j < NV; ++j) {
        float s2[H2];
        #pragma unroll
        for (int o = 0; o < H2; ++o) s2[o] = b2[j * H2 + o];

        const float* w1  = W1e + j * (H1 * NV);
        const float* w2t = W2T + j * (H1 * H2);
        const float* bb1 = b1  + j * H1;

        #pragma unroll 1
        for (int h = 0; h < H1; ++h) {
            float s = bb1[h];
            const float* w = w1 + h * NV;
            #pragma unroll
            for (int i = 0; i < NV; ++i) s += x[i] * w[i];
            float g = gelu_lut(s, tbl);
            const float* wr = w2t + h * H2;
            #pragma unroll
            for (int o = 0; o < H2; ++o) s2[o] += g * wr[o];
        }

        float r = b3[j];
        #pragma unroll
        for (int o = 0; o < H2; ++o) r += gelu_lut(s2[o], tbl) * W3[j * H2 + o];
        res[j] = r;
    }

    #pragma unroll
    for (int i = 0; i < 5; ++i) {
        float2 v; v.x = res[2 * i]; v.y = res[2 * i + 1];
        *reinterpret_cast<float2*>(out + (size_t)b * NV + 2 * i) = v;
    }
}

extern "C" void kernel_launch(void* const* d_in, const int* in_sizes, int n_in,
                              void* d_out, int out_size, void* d_ws, size_t ws_size,
                              hipStream_t stream) {
    const float* X  = (const float*)d_in[0];
    const float* Wl = (const float*)d_in[1];
    const float* W1 = (const float*)d_in[2];
    const float* b1 = (const float*)d_in[3];
    const float* W2 = (const float*)d_in[4];
    const float* b2 = (const float*)d_in[5];
    const float* W3 = (const float*)d_in[6];
    const float* b3 = (const float*)d_in[7];
    float* out = (float*)d_out;

    int B = in_sizes[0] / NV;                 // 500000
    float* Wout = out + (size_t)B * NV;       // output #2 (10x10 W) at the tail
    float* ws   = (float*)d_ws;               // 513 + 6400 + 20480 floats

    hipLaunchKernelGGL(prep_W, dim3(1), dim3(256), 0, stream, Wl, W1, W2, Wout, ws);

    int grid = (B + 255) / 256;
    hipLaunchKernelGGL(ncd_main, dim3(grid), dim3(256), 0, stream,
                       X, ws + WS_W1E, b1, ws + WS_W2T, b2, W3, b3, ws + WS_TBL, out, B);
}

// Round 9
// 208.214 us; speedup vs baseline: 13.5094x; 2.6052x over previous
//
#include <hip/hip_runtime.h>
#include <hip/hip_bf16.h>
#include <math.h>

#define NV  10
#define H1  64
#define H2  32

typedef __attribute__((ext_vector_type(8))) short bf16x8;
typedef __attribute__((ext_vector_type(4))) float f32x4;
typedef __attribute__((ext_vector_type(4))) unsigned int u32x4;

union frag_u { bf16x8 f; u32x4 u; unsigned int w[4]; };

#define MFMA(a,b,c) __builtin_amdgcn_mfma_f32_16x16x32_bf16(a, b, c, 0, 0, 0)

__device__ __forceinline__ unsigned short f2bf(float f) {
    union { __hip_bfloat16 h; unsigned short u; } cv;
    cv.h = __float2bfloat16(f);   // RNE
    return cv.u;
}
__device__ __forceinline__ unsigned int pack2(float lo, float hi) {
    return (unsigned)f2bf(lo) | ((unsigned)f2bf(hi) << 16);
}

// GELU: deg-11 odd poly for erf(x/sqrt2) on [-3,3]; |x|>3 -> max(x,0).
// Hand-fit (nodes 0.7/1.4/2.0/2.6/3.0, slope-exact at 0); |err|<=1.5e-3 inside,
// <=4e-3 at the |x|=3 boundary. 12 full-rate VALU ops: no TRANS (30-50cyc each,
// rounds 3-5), no LDS (24 lookups/lane/j would make DS the bottleneck).
__device__ __forceinline__ float gelu_poly(float x) {
    float p  = __builtin_amdgcn_fmed3f(x, -3.0f, 3.0f);
    float p2 = p * p;
    float t  = __builtin_fmaf(p2, -4.6113e-6f,    1.47439e-4f);
    t        = __builtin_fmaf(p2, t, -2.136050e-3f);
    t        = __builtin_fmaf(p2, t,  1.966256e-2f);
    t        = __builtin_fmaf(p2, t, -1.3288786e-1f);
    t        = __builtin_fmaf(p2, t,  7.9788456e-1f);
    float P  = p * t;
    float hx = 0.5f * x;
    float y  = __builtin_fmaf(hx, P, hx);
    float big = fmaxf(x, 0.0f);
    return (__builtin_fabsf(x) > 3.0f) ? big : y;
}

// ---------------------------------------------------------------------------
// Prep (1 block): adjacency mask -> Wout; W1 (adjacency+bias folded) and W2
// rearranged into exact MFMA A-fragment order as bf16 in ws.
// a1[(j*4+t)*64 + lane][8]: A-frag for GEMM1 h-tile t: row h=16t+(lane&15),
//   k=(lane>>4)*8+b; k<10 -> W1[j,h,k]*W[k,j]; k==10 -> b1[j,h]; else 0.
// a2[((j*2+t2)*2+ks)*64 + lane][8]: GEMM2 o-tile t2, K-step ks:
//   row o=16t2+(lane&15), h=32ks+(lane>>4)*8+b -> W2[j,o,h].
// ---------------------------------------------------------------------------
__global__ void prep_W(const float* __restrict__ Wl,
                       const float* __restrict__ W1,
                       const float* __restrict__ b1,
                       const float* __restrict__ W2,
                       float* __restrict__ Wout,
                       unsigned short* __restrict__ a1,
                       unsigned short* __restrict__ a2) {
    __shared__ float W[100];
    __shared__ float thrv;
    int t = threadIdx.x;   // 256 threads
    if (t < 100) {
        int i = t / NV, j = t % NV;
        float w = 1.0f / (1.0f + expf(-Wl[t]));
        if (i == j) w = 0.0f;
        W[t] = w;
    }
    __syncthreads();
    if (t < 100) {
        float v = W[t];
        int cnt = 0;
        #pragma unroll
        for (int k = 0; k < 100; ++k) cnt += (W[k] > v) ? 1 : 0;
        if (cnt == 29) thrv = v;   // exactly 29 strictly greater == 30th largest
    }
    __syncthreads();
    if (t < 100) {
        float v = W[t];
        float m = (v >= thrv) ? v : 0.0f;
        Wout[t] = m;
        W[t] = m;
    }
    __syncthreads();
    // a1 fragments: 10*4*64*8 = 20480 entries
    for (int n = t; n < 20480; n += 256) {
        int b = n & 7, l = (n >> 3) & 63, tt = (n >> 9) & 3, j = n >> 11;
        int h = 16 * tt + (l & 15);
        int k = ((l >> 4) << 3) + b;
        float val = 0.0f;
        if (k < 10)       val = W1[j * 640 + h * 10 + k] * W[k * NV + j];
        else if (k == 10) val = b1[j * 64 + h];
        a1[n] = f2bf(val);
    }
    // a2 fragments: 10*2*2*64*8 = 20480 entries
    for (int n = t; n < 20480; n += 256) {
        int b = n & 7, l = (n >> 3) & 63, ks = (n >> 9) & 1, t2 = (n >> 10) & 1, j = n >> 11;
        int o = 16 * t2 + (l & 15);
        int h = 32 * ks + ((l >> 4) << 3) + b;
        a2[n] = f2bf(W2[j * 2048 + o * 64 + h]);
    }
}

// ---------------------------------------------------------------------------
// Main: 1 wave = 16 samples. All GEMMs keep samples on the N (column) axis so
// the inter-layer handoff never needs a transpose: C-layout (h=16t'+4q+r) and
// next B-frag (h=32ks+8q+b) live in the same s=lane&15 column; the regroup is
// a per-wave-private 2KB LDS round-trip, XOR-swizzled (w ^= (s&7)<<2) so both
// writes and b128 reads are ~2-way (free, m136).
// ---------------------------------------------------------------------------
__global__ __launch_bounds__(256, 4) void ncd_mfma(
    const float* __restrict__ X,            // [B,10]
    const unsigned short* __restrict__ a1u, // frag-ordered W1eff+bias (bf16)
    const unsigned short* __restrict__ a2u, // frag-ordered W2 (bf16)
    const float* __restrict__ b2,           // [10,32]
    const float* __restrict__ W3,           // [10,32]
    const float* __restrict__ b3,           // [10]
    float* __restrict__ out,                // [B,10]
    int Bn, int ntiles)
{
    __shared__ float b2s[320];
    __shared__ float w3s[320];
    __shared__ unsigned xlds[4][512];       // per-wave 2KB handoff buffer

    for (int i = threadIdx.x; i < 320; i += 256) { b2s[i] = b2[i]; w3s[i] = W3[i]; }
    __syncthreads();

    const int wave = threadIdx.x >> 6;
    const int lane = threadIdx.x & 63;
    const int q = lane >> 4;
    const int s = lane & 15;
    const int tile = blockIdx.x * 4 + wave;
    if (tile >= ntiles) return;
    const int sbase = tile * 16;

    // --- B-frag of GEMM1: X row s, k = q*8+b (k=10 -> bias slot 1.0) ---
    int row = sbase + s; if (row > Bn - 1) row = Bn - 1;
    const float* xr = X + (size_t)row * 10;
    frag_u xb;
    if (q == 0) {
        float2 v0 = *(const float2*)(xr + 0), v1 = *(const float2*)(xr + 2);
        float2 v2 = *(const float2*)(xr + 4), v3 = *(const float2*)(xr + 6);
        xb.w[0] = pack2(v0.x, v0.y); xb.w[1] = pack2(v1.x, v1.y);
        xb.w[2] = pack2(v2.x, v2.y); xb.w[3] = pack2(v3.x, v3.y);
    } else if (q == 1) {
        float2 v4 = *(const float2*)(xr + 8);
        xb.w[0] = pack2(v4.x, v4.y);
        xb.w[1] = pack2(1.0f, 0.0f);          // k=10: bias slot
        xb.w[2] = 0u; xb.w[3] = 0u;
    } else {
        xb.w[0] = xb.w[1] = xb.w[2] = xb.w[3] = 0u;
    }

    const bf16x8* A1 = (const bf16x8*)a1u;
    const bf16x8* A2 = (const bf16x8*)a2u;
    unsigned* wb = xlds[wave];
    const int sw = (s & 7) << 2;
    const f32x4 zf = {0.0f, 0.0f, 0.0f, 0.0f};

    #pragma unroll 1
    for (int j = 0; j < NV; ++j) {
        // --- GEMM1: 4 h-tiles ---
        f32x4 acc[4];
        #pragma unroll
        for (int tt = 0; tt < 4; ++tt) {
            frag_u af; af.f = A1[(j * 4 + tt) * 64 + lane];
            acc[tt] = MFMA(af.f, xb.f, zf);
        }
        // --- GELU + pack + swizzled per-wave LDS write ---
        #pragma unroll
        for (int tt = 0; tt < 4; ++tt) {
            float g0 = gelu_poly(acc[tt][0]);
            float g1 = gelu_poly(acc[tt][1]);
            float g2 = gelu_poly(acc[tt][2]);
            float g3 = gelu_poly(acc[tt][3]);
            int w0 = 8 * tt + 2 * q;
            wb[s * 32 + ((w0    ) ^ sw)] = pack2(g0, g1);
            wb[s * 32 + ((w0 + 1) ^ sw)] = pack2(g2, g3);
        }
        // --- GEMM2: 2 o-tiles x 2 K-steps ---
        f32x4 acc2[2] = {zf, zf};
        #pragma unroll
        for (int ks = 0; ks < 2; ++ks) {
            frag_u bf;
            bf.u = *(const u32x4*)&wb[s * 32 + ((16 * ks + 4 * q) ^ sw)];
            #pragma unroll
            for (int t2 = 0; t2 < 2; ++t2) {
                frag_u af; af.f = A2[((j * 2 + t2) * 2 + ks) * 64 + lane];
                acc2[t2] = MFMA(af.f, bf.f, acc2[t2]);
            }
        }
        // --- bias + GELU + head dot + quarter-lane reduce ---
        float partial = 0.0f;
        #pragma unroll
        for (int t2 = 0; t2 < 2; ++t2) {
            float4 b2v = *(const float4*)&b2s[j * 32 + 16 * t2 + 4 * q];
            float4 w3v = *(const float4*)&w3s[j * 32 + 16 * t2 + 4 * q];
            partial += gelu_poly(acc2[t2][0] + b2v.x) * w3v.x;
            partial += gelu_poly(acc2[t2][1] + b2v.y) * w3v.y;
            partial += gelu_poly(acc2[t2][2] + b2v.z) * w3v.z;
            partial += gelu_poly(acc2[t2][3] + b2v.w) * w3v.w;
        }
        partial += __shfl_xor(partial, 16);
        partial += __shfl_xor(partial, 32);
        float rj = partial + b3[j];
        if (lane < 16 && sbase + lane < Bn) {
            out[(size_t)(sbase + lane) * 10 + j] = rj;
        }
    }
}

extern "C" void kernel_launch(void* const* d_in, const int* in_sizes, int n_in,
                              void* d_out, int out_size, void* d_ws, size_t ws_size,
                              hipStream_t stream) {
    const float* X  = (const float*)d_in[0];
    const float* Wl = (const float*)d_in[1];
    const float* W1 = (const float*)d_in[2];
    const float* b1 = (const float*)d_in[3];
    const float* W2 = (const float*)d_in[4];
    const float* b2 = (const float*)d_in[5];
    const float* W3 = (const float*)d_in[6];
    const float* b3 = (const float*)d_in[7];
    float* out = (float*)d_out;

    int B = in_sizes[0] / NV;                 // 500000
    float* Wout = out + (size_t)B * NV;       // output #2 (10x10 W) at the tail
    unsigned short* a1 = (unsigned short*)d_ws;        // 20480 bf16 = 40KB
    unsigned short* a2 = a1 + 20480;                   // 20480 bf16 = 40KB

    hipLaunchKernelGGL(prep_W, dim3(1), dim3(256), 0, stream,
                       Wl, W1, b1, W2, Wout, a1, a2);

    int ntiles = (B + 15) / 16;
    int blocks = (ntiles + 3) / 4;
    hipLaunchKernelGGL(ncd_mfma, dim3(blocks), dim3(256), 0, stream,
                       X, a1, a2, b2, W3, b3, out, B, ntiles);
}